// Round 7
// baseline (444.753 us; speedup 1.0000x reference)
//
#include <hip/hip_runtime.h>

// Problem constants (from reference)
#define NN 50000
#define EE 800000
#define KIN 512
#define HF 256      // H*OUT
#define NH 8
#define FOUT 32
#define NC 16
#define NEG 0.2f
#define NB_SCAN 196  // ceil(NN/256)

typedef unsigned short u16;
typedef __attribute__((ext_vector_type(8))) short shortx8;   // 8 bf16 (4 VGPRs) MFMA A/B frag
typedef __attribute__((ext_vector_type(4))) float floatx4;   // MFMA C/D frag
typedef __attribute__((ext_vector_type(8))) unsigned short ushortx8;
typedef __attribute__((ext_vector_type(4))) unsigned short ushortx4;
typedef __attribute__((ext_vector_type(4))) unsigned uintx4;

__device__ __forceinline__ float lrelu(float x) { return x > 0.f ? x : NEG * x; }

__device__ __forceinline__ u16 f2bf(float f) {
    unsigned u = __float_as_uint(f);
    return (u16)((u + 0x7FFFu + ((u >> 16) & 1u)) >> 16);   // RNE
}
__device__ __forceinline__ float bf2f(u16 v) {
    return __uint_as_float((unsigned)v << 16);
}
// pack two fp32 -> (bf16(a) | bf16(b)<<16), round-half-up (bias 2^-25, negligible)
__device__ __forceinline__ unsigned pk2bf(float a, float b) {
    unsigned ua = __float_as_uint(a), ub = __float_as_uint(b);
    return ((ua + 0x8000u) >> 16) | ((ub + 0x8000u) & 0xffff0000u);
}

__device__ __forceinline__ void gll16(const void* g, void* l) {
    // async global->LDS, 16B/lane; LDS dest = wave-uniform base + lane*16
    __builtin_amdgcn_global_load_lds((const __attribute__((address_space(1))) void*)g,
                                     (__attribute__((address_space(3))) void*)l, 16, 0, 0);
}

// ---------------- CSR count + weight converts (merged kernel) ----------------
__global__ void count_deg_convw(const int* __restrict__ dst, int* __restrict__ deg,
                                const float* __restrict__ W1, const float* __restrict__ W2,
                                u16* __restrict__ w1t, u16* __restrict__ w2t) {
    int e = blockIdx.x * 256 + threadIdx.x;
    if (e < EE) atomicAdd(&deg[dst[e]], 1);
    if (e < KIN * HF) {                        // W1 [512,256] -> w1t [256,512] bf16
        int k = e >> 8, n = e & 255;
        w1t[n * KIN + k] = f2bf(W1[e]);
    } else if (e < KIN * HF + HF * NC) {       // W2 [256,16] -> w2t [16,256] bf16
        int e2 = e - KIN * HF;
        int k = e2 >> 4, c = e2 & 15;
        w2t[c * HF + k] = f2bf(W2[e2]);
    }
}

__global__ __launch_bounds__(256) void scan_a(const int* __restrict__ deg, int* __restrict__ bsum) {
    __shared__ int sm[256];
    int t = threadIdx.x;
    int i = blockIdx.x * 256 + t;
    sm[t] = (i < NN) ? deg[i] : 0;
    __syncthreads();
    for (int o = 128; o; o >>= 1) { if (t < o) sm[t] += sm[t + o]; __syncthreads(); }
    if (t == 0) bsum[blockIdx.x] = sm[0];
}

__global__ __launch_bounds__(256) void scan_b(const int* __restrict__ bsum, int* __restrict__ boff) {
    __shared__ int sm[256];
    int t = threadIdx.x;
    sm[t] = (t < NB_SCAN) ? bsum[t] : 0;
    __syncthreads();
    for (int d = 1; d < 256; d <<= 1) {
        int v = (t >= d) ? sm[t - d] : 0;
        __syncthreads();
        sm[t] += v;
        __syncthreads();
    }
    if (t < NB_SCAN) boff[t] = (t == 0) ? 0 : sm[t - 1];
}

__global__ __launch_bounds__(256) void scan_c(const int* __restrict__ deg, const int* __restrict__ boff,
                                              int* __restrict__ off) {
    __shared__ int sm[256];
    int t = threadIdx.x;
    int i = blockIdx.x * 256 + t;
    int d = (i < NN) ? deg[i] : 0;
    sm[t] = d;
    __syncthreads();
    for (int dd = 1; dd < 256; dd <<= 1) {
        int v = (t >= dd) ? sm[t - dd] : 0;
        __syncthreads();
        sm[t] += v;
        __syncthreads();
    }
    if (i < NN) off[i] = boff[blockIdx.x] + sm[t] - d;
    if (i == 0) off[NN] = EE;
}

__global__ void fill_csr(const int* __restrict__ src, const int* __restrict__ dst,
                         const int* __restrict__ off, int* __restrict__ cursor,
                         int* __restrict__ csr_src) {
    int e = blockIdx.x * 256 + threadIdx.x;
    if (e < EE) {
        int d = dst[e];
        int pos = atomicAdd(&cursor[d], 1);
        csr_src[off[d] + pos] = src[e];
    }
}

// ---------------- GEMM1 (bf16 MFMA, fused x-convert + fused scores) ----------------
// h1b[N,256] = bf16(x)[N,512] @ W1T^T ; es_t/ed_t[h][n] from fp32 acc in epilogue.
// Tile 128x256 (full width). 4 waves, each 64 rows x 128 cols = 4x8 MFMA tiles.
__global__ __launch_bounds__(256, 2) void gemm1_mfma(const float* __restrict__ x,
                                                     const u16* __restrict__ w1t,
                                                     u16* __restrict__ h1b,
                                                     const float* __restrict__ a1s,
                                                     const float* __restrict__ a1d,
                                                     float* __restrict__ est,
                                                     float* __restrict__ edt) {
    __shared__ __align__(16) float As[128 * 32];   // [row][k] fp32, 16 KB
    __shared__ __align__(16) u16 Bs[256 * 32];     // [col][k] bf16, 16 KB
    int t = threadIdx.x;
    int lane = t & 63, wave = t >> 6;
    int wm = wave >> 1, wn = wave & 1;
    int lm = lane & 15, quad = lane >> 4;
    int bm = blockIdx.x * 128;

    floatx4 acc[4][8];
#pragma unroll
    for (int i = 0; i < 4; i++)
#pragma unroll
        for (int j = 0; j < 8; j++) acc[i][j] = (floatx4){0.f, 0.f, 0.f, 0.f};

    // A staging: wave covers rows wave*32..+31 ; 4 insts x 8 rows (fp32, 4 floats/lane)
    int arow_l = wave * 32 + (lane >> 3);
    int akoff = (lane & 7) * 4;
    const float* aptr[4];
#pragma unroll
    for (int i = 0; i < 4; i++) {
        int ar = bm + arow_l + i * 8;
        if (ar > NN - 1) ar = NN - 1;     // tail dup-reads; writes guarded
        aptr[i] = x + (size_t)ar * KIN + akoff;
    }
    float* alds[4];
#pragma unroll
    for (int i = 0; i < 4; i++) alds[i] = As + (wave * 32 + i * 8) * 32;

    // B staging: wave covers cols wave*64..+63 ; 4 insts x 16 rows (bf16, 8 elems/lane)
    int brow_l = wave * 64 + (lane >> 2);
    int bkoff = (lane & 3) * 8;
    const u16* bptr[4];
#pragma unroll
    for (int i = 0; i < 4; i++) bptr[i] = w1t + (size_t)(brow_l + i * 16) * KIN + bkoff;
    u16* blds[4];
#pragma unroll
    for (int i = 0; i < 4; i++) blds[i] = Bs + (wave * 64 + i * 16) * 32;

    int offA[4], offB[8];
#pragma unroll
    for (int i = 0; i < 4; i++) offA[i] = (wm * 64 + i * 16 + lm) * 32 + quad * 8;
#pragma unroll
    for (int j = 0; j < 8; j++) offB[j] = (wn * 128 + j * 16 + lm) * 32 + quad * 8;

    for (int kk = 0; kk < KIN; kk += 32) {
#pragma unroll
        for (int i = 0; i < 4; i++) gll16(aptr[i] + kk, alds[i]);
#pragma unroll
        for (int i = 0; i < 4; i++) gll16(bptr[i] + kk, blds[i]);
        __syncthreads();
        shortx8 af[4], bf[8];
#pragma unroll
        for (int i = 0; i < 4; i++) {
            const float4* ap = (const float4*)&As[offA[i]];
            float4 lo = ap[0], hi = ap[1];
            union { uintx4 u; shortx8 s; } cv;
            cv.u[0] = pk2bf(lo.x, lo.y);
            cv.u[1] = pk2bf(lo.z, lo.w);
            cv.u[2] = pk2bf(hi.x, hi.y);
            cv.u[3] = pk2bf(hi.z, hi.w);
            af[i] = cv.s;
        }
#pragma unroll
        for (int j = 0; j < 8; j++) bf[j] = *(const shortx8*)&Bs[offB[j]];
#pragma unroll
        for (int i = 0; i < 4; i++)
#pragma unroll
            for (int j = 0; j < 8; j++)
                acc[i][j] = __builtin_amdgcn_mfma_f32_16x16x32_bf16(af[i], bf[j], acc[i][j], 0, 0, 0);
        __syncthreads();
    }

    // epilogue 1: h1 store. C/D map col=lane&15, row=quad*4+reg -> bf16
#pragma unroll
    for (int i = 0; i < 4; i++) {
        int row = bm + wm * 64 + i * 16 + quad * 4;
#pragma unroll
        for (int j = 0; j < 8; j++) {
            int col = wn * 128 + j * 16 + lm;
#pragma unroll
            for (int r = 0; r < 4; r++) {
                if (row + r < NN) h1b[(size_t)(row + r) * HF + col] = f2bf(acc[i][j][r]);
            }
        }
    }

    // epilogue 2: fused per-node scores (transposed layout es_t/ed_t[h][n]).
    // a1s/a1d flat [256] index == global col. Head h' (within this wn half): cols j=2h',2h'+1.
    float as_v[8], ad_v[8];
#pragma unroll
    for (int j = 0; j < 8; j++) {
        int col = wn * 128 + j * 16 + lm;
        as_v[j] = a1s[col];
        ad_v[j] = a1d[col];
    }
#pragma unroll
    for (int i = 0; i < 4; i++) {
#pragma unroll
        for (int r = 0; r < 4; r++) {
            int row = bm + wm * 64 + i * 16 + quad * 4 + r;
#pragma unroll
            for (int hp = 0; hp < 4; hp++) {
                float e_s = acc[i][2 * hp][r] * as_v[2 * hp] + acc[i][2 * hp + 1][r] * as_v[2 * hp + 1];
                float e_d = acc[i][2 * hp][r] * ad_v[2 * hp] + acc[i][2 * hp + 1][r] * ad_v[2 * hp + 1];
#pragma unroll
                for (int o = 8; o; o >>= 1) {
                    e_s += __shfl_down(e_s, o, 16);
                    e_d += __shfl_down(e_d, o, 16);
                }
                if (lm == 0 && row < NN) {
                    int h = wn * 4 + hp;
                    est[(size_t)h * NN + row] = e_s;
                    edt[(size_t)h * NN + row] = e_d;
                }
            }
        }
    }
}

// ---------------- layer-1 softmax aggregate (+ ELU): head-sliced for XCD L2 residency ----------------
// grid = (NN/8) * 8; head = blockIdx & 7 (round-robin XCD swizzle -> slice k hot in XCD k's L2).
// Per-slice footprint: h1 slice 3.2MB + es_t col 200KB + ed_t col 200KB < 4MB XCD L2.
// wave = 2 nodes sequential; lane = 8 edge-slots x 8 feature-quads; 64B/edge gather (one line).
__global__ __launch_bounds__(256) void agg1(const u16* __restrict__ h1b, const float* __restrict__ est,
                                            const float* __restrict__ edt, const int* __restrict__ off,
                                            const int* __restrict__ csr_src, u16* __restrict__ out1b) {
    int head = blockIdx.x & 7;
    int grp  = blockIdx.x >> 3;
    int wave = threadIdx.x >> 6;
    int lane = threadIdx.x & 63;
    int slot = lane >> 3;       // edge slot 0..7
    int fq   = lane & 7;        // features head*32 + fq*4 .. +3
    const float* esh = est + (size_t)head * NN;
    const float* edh_p = edt + (size_t)head * NN;
    const u16* hbase = h1b + head * 32 + fq * 4;
#pragma unroll
    for (int rep = 0; rep < 2; rep++) {
        int n = grp * 8 + wave * 2 + rep;   // NN % 8 == 0
        int beg = off[n];
        int deg = off[n + 1] - beg;
        float edh = edh_p[n];
        float a0 = 0.f, a1 = 0.f, a2 = 0.f, a3 = 0.f, sp = 0.f;
        for (int base = 0; base < deg; base += 8) {
            int sv = (lane < 8 && base + lane < deg) ? csr_src[beg + base + lane] : 0;
            int s = __shfl(sv, slot, 64);
            if (base + slot < deg) {
                float lg = esh[s] + edh;
                float p = __expf(lg > 0.f ? lg : NEG * lg);
                ushortx4 hv = *(const ushortx4*)(hbase + (size_t)s * HF);
                sp += p;
                a0 += p * bf2f(hv[0]);
                a1 += p * bf2f(hv[1]);
                a2 += p * bf2f(hv[2]);
                a3 += p * bf2f(hv[3]);
            }
        }
        // reduce over the 8 slots (stride-8 lanes)
#pragma unroll
        for (int o = 32; o >= 8; o >>= 1) {
            a0 += __shfl_down(a0, o, 64);
            a1 += __shfl_down(a1, o, 64);
            a2 += __shfl_down(a2, o, 64);
            a3 += __shfl_down(a3, o, 64);
            sp += __shfl_down(sp, o, 64);
        }
        if (lane < 8) {
            float inv = sp > 0.f ? 1.0f / sp : 0.f;
            float v0 = a0 * inv, v1 = a1 * inv, v2 = a2 * inv, v3 = a3 * inv;
            v0 = v0 > 0.f ? v0 : (__expf(v0) - 1.0f);   // fused ELU
            v1 = v1 > 0.f ? v1 : (__expf(v1) - 1.0f);
            v2 = v2 > 0.f ? v2 : (__expf(v2) - 1.0f);
            v3 = v3 > 0.f ? v3 : (__expf(v3) - 1.0f);
            uint2 ob;
            ob.x = (unsigned)f2bf(v0) | ((unsigned)f2bf(v1) << 16);
            ob.y = (unsigned)f2bf(v2) | ((unsigned)f2bf(v3) << 16);
            *(uint2*)(out1b + (size_t)n * HF + head * 32 + fq * 4) = ob;
        }
    }
}

// ---------------- GEMM2 (1-wave MFMA) + layer-2 scores ----------------
__global__ __launch_bounds__(64) void gemm2_mfma(const u16* __restrict__ out1b, const u16* __restrict__ w2t,
                                                 const float* __restrict__ a2s, const float* __restrict__ a2d,
                                                 float* __restrict__ h2, float* __restrict__ es2,
                                                 float* __restrict__ ed2) {
    int lane = threadIdx.x;
    int lm = lane & 15, quad = lane >> 4;
    int nb = blockIdx.x * 16;
    floatx4 acc = (floatx4){0.f, 0.f, 0.f, 0.f};
    const u16* arow = out1b + (size_t)(nb + lm) * HF + quad * 8;
    const u16* brow = w2t + lm * HF + quad * 8;
#pragma unroll
    for (int kk = 0; kk < HF; kk += 32) {
        shortx8 af = *(const shortx8*)(arow + kk);
        shortx8 bf = *(const shortx8*)(brow + kk);
        acc = __builtin_amdgcn_mfma_f32_16x16x32_bf16(af, bf, acc, 0, 0, 0);
    }
    float a2sc = a2s[lm], a2dc = a2d[lm];
#pragma unroll
    for (int r = 0; r < 4; r++) {
        int n = nb + quad * 4 + r;
        float v = acc[r];
        h2[n * NC + lm] = v;
        float ps = v * a2sc, pd = v * a2dc;
#pragma unroll
        for (int o = 8; o; o >>= 1) {
            ps += __shfl_down(ps, o, 16);
            pd += __shfl_down(pd, o, 16);
        }
        if (lm == 0) { es2[n] = ps; ed2[n] = pd; }
    }
}

// ---------------- layer-2 aggregate + log_softmax: 16 nodes x 16 classes ----------------
__global__ __launch_bounds__(256) void agg2(const float* __restrict__ h2, const float* __restrict__ es2,
                                            const float* __restrict__ ed2, const int* __restrict__ off,
                                            const int* __restrict__ csr_src, float* __restrict__ out) {
    int t = threadIdx.x;
    int nid = blockIdx.x * 16 + (t >> 4);   // NN % 16 == 0
    int c = t & 15;
    int beg = off[nid];
    int deg = off[nid + 1] - beg;
    float edn = ed2[nid];
    float s = 0.f, acc = 0.f;
    for (int base = 0; base < deg; base += 16) {
        int nch = deg - base; if (nch > 16) nch = 16;
        int sv = 0;
        if (c < nch) sv = csr_src[beg + base + c];
        int sva[16];
#pragma unroll
        for (int e = 0; e < 16; e++) sva[e] = __shfl(sv, e, 16);
        float hva[16];
#pragma unroll
        for (int e = 0; e < 16; e++) hva[e] = h2[sva[e] * NC + c];  // e>=nch reads row 0: masked by p=0
        float p = 0.f;
        if (c < nch) p = __expf(lrelu(es2[sv] + edn));
        s += p;
        float pa[16];
#pragma unroll
        for (int e = 0; e < 16; e++) pa[e] = __shfl(p, e, 16);
#pragma unroll
        for (int e = 0; e < 16; e++) acc += pa[e] * hva[e];
    }
#pragma unroll
    for (int o = 8; o; o >>= 1) s += __shfl_down(s, o, 16);
    s = __shfl(s, 0, 16);
    float v = (s > 0.f) ? acc / s : 0.f;
    float m2 = v;
#pragma unroll
    for (int o = 8; o; o >>= 1) m2 = fmaxf(m2, __shfl_down(m2, o, 16));
    m2 = __shfl(m2, 0, 16);
    float se = __expf(v - m2);
#pragma unroll
    for (int o = 8; o; o >>= 1) se += __shfl_down(se, o, 16);
    se = __shfl(se, 0, 16);
    out[nid * NC + c] = v - m2 - __logf(se);
}

extern "C" void kernel_launch(void* const* d_in, const int* in_sizes, int n_in,
                              void* d_out, int out_size, void* d_ws, size_t ws_size,
                              hipStream_t stream) {
    const float* x   = (const float*)d_in[0];
    const float* W1  = (const float*)d_in[1];
    const float* a1s = (const float*)d_in[2];
    const float* a1d = (const float*)d_in[3];
    const float* W2  = (const float*)d_in[4];
    const float* a2s = (const float*)d_in[5];
    const float* a2d = (const float*)d_in[6];
    const int*   ei  = (const int*)d_in[7];
    const int* srcv = ei;
    const int* dstv = ei + EE;
    float* out = (float*)d_out;

    // workspace (~62 MB)
    u16* h1b    = (u16*)d_ws;                         // N*256 bf16
    u16* out1b  = h1b + (size_t)NN * HF;              // N*256 bf16
    float* est  = (float*)(out1b + (size_t)NN * HF);  // 8*N (transposed scores)
    float* edt  = est + (size_t)NH * NN;              // 8*N
    float* h2   = edt + (size_t)NH * NN;              // N*16
    float* es2v = h2 + (size_t)NN * NC;               // N
    float* ed2v = es2v + NN;                          // N
    int* deg    = (int*)(ed2v + NN);                  // N   (deg+cursor contiguous: one memset)
    int* cursor = deg + NN;                           // N
    int* offs   = cursor + NN;                        // N+1
    int* csr    = offs + NN + 1;                      // E
    int* bsum   = csr + EE;                           // 256
    int* boff   = bsum + 256;                         // 256
    u16* w1t    = (u16*)(boff + 256);                 // 256*512 bf16
    u16* w2t    = w1t + (size_t)HF * KIN;             // 16*256 bf16

    hipMemsetAsync(deg, 0, 2 * NN * sizeof(int), stream);
    count_deg_convw<<<(EE + 255) / 256, 256, 0, stream>>>(dstv, deg, W1, W2, w1t, w2t);
    scan_a<<<NB_SCAN, 256, 0, stream>>>(deg, bsum);
    scan_b<<<1, 256, 0, stream>>>(bsum, boff);
    scan_c<<<NB_SCAN, 256, 0, stream>>>(deg, boff, offs);
    fill_csr<<<(EE + 255) / 256, 256, 0, stream>>>(srcv, dstv, offs, cursor, csr);
    gemm1_mfma<<<(NN + 127) / 128, 256, 0, stream>>>(x, w1t, h1b, a1s, a1d, est, edt);
    agg1<<<(NN / 8) * 8, 256, 0, stream>>>(h1b, est, edt, offs, csr, out1b);
    gemm2_mfma<<<NN / 16, 64, 0, stream>>>(out1b, w2t, a2s, a2d, h2, es2v, ed2v);
    agg2<<<NN / 16, 256, 0, stream>>>(h2, es2v, ed2v, offs, csr, out);
}

// Round 8
// 360.228 us; speedup vs baseline: 1.2346x; 1.2346x over previous
//
#include <hip/hip_runtime.h>

// Problem constants (from reference)
#define NN 50000
#define EE 800000
#define KIN 512
#define HF 256      // H*OUT
#define NH 8
#define FOUT 32
#define NC 16
#define NEG 0.2f
#define NB_SCAN 196  // ceil(NN/256)

typedef unsigned short u16;
typedef __attribute__((ext_vector_type(8))) short shortx8;   // 8 bf16 (4 VGPRs) MFMA A/B frag
typedef __attribute__((ext_vector_type(4))) float floatx4;   // MFMA C/D frag
typedef __attribute__((ext_vector_type(8))) unsigned short ushortx8;
typedef __attribute__((ext_vector_type(4))) unsigned uintx4;

__device__ __forceinline__ float lrelu(float x) { return x > 0.f ? x : NEG * x; }

__device__ __forceinline__ u16 f2bf(float f) {
    unsigned u = __float_as_uint(f);
    return (u16)((u + 0x7FFFu + ((u >> 16) & 1u)) >> 16);   // RNE
}
__device__ __forceinline__ float bf2f(u16 v) {
    return __uint_as_float((unsigned)v << 16);
}
// pack two fp32 -> (bf16(a) | bf16(b)<<16), round-half-up (bias 2^-25, negligible)
__device__ __forceinline__ unsigned pk2bf(float a, float b) {
    unsigned ua = __float_as_uint(a), ub = __float_as_uint(b);
    return ((ua + 0x8000u) >> 16) | ((ub + 0x8000u) & 0xffff0000u);
}

__device__ __forceinline__ void gll16(const void* g, void* l) {
    // async global->LDS, 16B/lane; LDS dest = wave-uniform base + lane*16
    __builtin_amdgcn_global_load_lds((const __attribute__((address_space(1))) void*)g,
                                     (__attribute__((address_space(3))) void*)l, 16, 0, 0);
}

// ---------------- CSR count + weight converts (merged kernel) ----------------
__global__ void count_deg_convw(const int* __restrict__ dst, int* __restrict__ deg,
                                const float* __restrict__ W1, const float* __restrict__ W2,
                                u16* __restrict__ w1t, u16* __restrict__ w2t) {
    int e = blockIdx.x * 256 + threadIdx.x;
    if (e < EE) atomicAdd(&deg[dst[e]], 1);
    if (e < KIN * HF) {                        // W1 [512,256] -> w1t [256,512] bf16
        int k = e >> 8, n = e & 255;
        w1t[n * KIN + k] = f2bf(W1[e]);
    } else if (e < KIN * HF + HF * NC) {       // W2 [256,16] -> w2t [16,256] bf16
        int e2 = e - KIN * HF;
        int k = e2 >> 4, c = e2 & 15;
        w2t[c * HF + k] = f2bf(W2[e2]);
    }
}

__global__ __launch_bounds__(256) void scan_a(const int* __restrict__ deg, int* __restrict__ bsum) {
    __shared__ int sm[256];
    int t = threadIdx.x;
    int i = blockIdx.x * 256 + t;
    sm[t] = (i < NN) ? deg[i] : 0;
    __syncthreads();
    for (int o = 128; o; o >>= 1) { if (t < o) sm[t] += sm[t + o]; __syncthreads(); }
    if (t == 0) bsum[blockIdx.x] = sm[0];
}

// per-block scan; block offset derived in-kernel from bsum (scan_b merged away)
__global__ __launch_bounds__(256) void scan_c(const int* __restrict__ deg, const int* __restrict__ bsum,
                                              int* __restrict__ off) {
    __shared__ int sm[256];
    __shared__ int pre[256];
    int t = threadIdx.x;
    // block-prefix: sum of bsum[0..blockIdx-1]
    pre[t] = (t < blockIdx.x && t < NB_SCAN) ? bsum[t] : 0;
    __syncthreads();
    for (int o = 128; o; o >>= 1) { if (t < o) pre[t] += pre[t + o]; __syncthreads(); }
    int bofs = pre[0];
    __syncthreads();
    int i = blockIdx.x * 256 + t;
    int d = (i < NN) ? deg[i] : 0;
    sm[t] = d;
    __syncthreads();
    for (int dd = 1; dd < 256; dd <<= 1) {
        int v = (t >= dd) ? sm[t - dd] : 0;
        __syncthreads();
        sm[t] += v;
        __syncthreads();
    }
    if (i < NN) off[i] = bofs + sm[t] - d;
    if (i == 0) off[NN] = EE;
}

__global__ void fill_csr(const int* __restrict__ src, const int* __restrict__ dst,
                         const int* __restrict__ off, int* __restrict__ cursor,
                         int* __restrict__ csr_src) {
    int e = blockIdx.x * 256 + threadIdx.x;
    if (e < EE) {
        int d = dst[e];
        int pos = atomicAdd(&cursor[d], 1);
        csr_src[off[d] + pos] = src[e];
    }
}

// ---------------- GEMM1 (bf16 MFMA, fused x-convert + fused scores) ----------------
// h1b[N,256] = bf16(x)[N,512] @ W1T^T ; es1/ed1[n*8+h] (interleaved) from fp32 acc in epilogue.
// Tile 128x256 (full width). 4 waves, each 64 rows x 128 cols = 4x8 MFMA tiles.
__global__ __launch_bounds__(256, 2) void gemm1_mfma(const float* __restrict__ x,
                                                     const u16* __restrict__ w1t,
                                                     u16* __restrict__ h1b,
                                                     const float* __restrict__ a1s,
                                                     const float* __restrict__ a1d,
                                                     float* __restrict__ es1,
                                                     float* __restrict__ ed1) {
    __shared__ __align__(16) float As[128 * 32];   // [row][k] fp32, 16 KB
    __shared__ __align__(16) u16 Bs[256 * 32];     // [col][k] bf16, 16 KB
    int t = threadIdx.x;
    int lane = t & 63, wave = t >> 6;
    int wm = wave >> 1, wn = wave & 1;
    int lm = lane & 15, quad = lane >> 4;
    int bm = blockIdx.x * 128;

    floatx4 acc[4][8];
#pragma unroll
    for (int i = 0; i < 4; i++)
#pragma unroll
        for (int j = 0; j < 8; j++) acc[i][j] = (floatx4){0.f, 0.f, 0.f, 0.f};

    // A staging: wave covers rows wave*32..+31 ; 4 insts x 8 rows (fp32, 4 floats/lane)
    int arow_l = wave * 32 + (lane >> 3);
    int akoff = (lane & 7) * 4;
    const float* aptr[4];
#pragma unroll
    for (int i = 0; i < 4; i++) {
        int ar = bm + arow_l + i * 8;
        if (ar > NN - 1) ar = NN - 1;     // tail dup-reads; writes guarded
        aptr[i] = x + (size_t)ar * KIN + akoff;
    }
    float* alds[4];
#pragma unroll
    for (int i = 0; i < 4; i++) alds[i] = As + (wave * 32 + i * 8) * 32;

    // B staging: wave covers cols wave*64..+63 ; 4 insts x 16 rows (bf16, 8 elems/lane)
    int brow_l = wave * 64 + (lane >> 2);
    int bkoff = (lane & 3) * 8;
    const u16* bptr[4];
#pragma unroll
    for (int i = 0; i < 4; i++) bptr[i] = w1t + (size_t)(brow_l + i * 16) * KIN + bkoff;
    u16* blds[4];
#pragma unroll
    for (int i = 0; i < 4; i++) blds[i] = Bs + (wave * 64 + i * 16) * 32;

    int offA[4], offB[8];
#pragma unroll
    for (int i = 0; i < 4; i++) offA[i] = (wm * 64 + i * 16 + lm) * 32 + quad * 8;
#pragma unroll
    for (int j = 0; j < 8; j++) offB[j] = (wn * 128 + j * 16 + lm) * 32 + quad * 8;

    for (int kk = 0; kk < KIN; kk += 32) {
#pragma unroll
        for (int i = 0; i < 4; i++) gll16(aptr[i] + kk, alds[i]);
#pragma unroll
        for (int i = 0; i < 4; i++) gll16(bptr[i] + kk, blds[i]);
        __syncthreads();
        shortx8 af[4], bf[8];
#pragma unroll
        for (int i = 0; i < 4; i++) {
            const float4* ap = (const float4*)&As[offA[i]];
            float4 lo = ap[0], hi = ap[1];
            union { uintx4 u; shortx8 s; } cv;
            cv.u[0] = pk2bf(lo.x, lo.y);
            cv.u[1] = pk2bf(lo.z, lo.w);
            cv.u[2] = pk2bf(hi.x, hi.y);
            cv.u[3] = pk2bf(hi.z, hi.w);
            af[i] = cv.s;
        }
#pragma unroll
        for (int j = 0; j < 8; j++) bf[j] = *(const shortx8*)&Bs[offB[j]];
#pragma unroll
        for (int i = 0; i < 4; i++)
#pragma unroll
            for (int j = 0; j < 8; j++)
                acc[i][j] = __builtin_amdgcn_mfma_f32_16x16x32_bf16(af[i], bf[j], acc[i][j], 0, 0, 0);
        __syncthreads();
    }

    // epilogue 1: h1 store. C/D map col=lane&15, row=quad*4+reg -> bf16
#pragma unroll
    for (int i = 0; i < 4; i++) {
        int row = bm + wm * 64 + i * 16 + quad * 4;
#pragma unroll
        for (int j = 0; j < 8; j++) {
            int col = wn * 128 + j * 16 + lm;
#pragma unroll
            for (int r = 0; r < 4; r++) {
                if (row + r < NN) h1b[(size_t)(row + r) * HF + col] = f2bf(acc[i][j][r]);
            }
        }
    }

    // epilogue 2: fused per-node scores, interleaved es1/ed1[n*8+h].
    // Head h' within this wn half covers cols j=2h',2h'+1.
    float as_v[8], ad_v[8];
#pragma unroll
    for (int j = 0; j < 8; j++) {
        int col = wn * 128 + j * 16 + lm;
        as_v[j] = a1s[col];
        ad_v[j] = a1d[col];
    }
#pragma unroll
    for (int i = 0; i < 4; i++) {
#pragma unroll
        for (int r = 0; r < 4; r++) {
            int row = bm + wm * 64 + i * 16 + quad * 4 + r;
#pragma unroll
            for (int hp = 0; hp < 4; hp++) {
                float e_s = acc[i][2 * hp][r] * as_v[2 * hp] + acc[i][2 * hp + 1][r] * as_v[2 * hp + 1];
                float e_d = acc[i][2 * hp][r] * ad_v[2 * hp] + acc[i][2 * hp + 1][r] * ad_v[2 * hp + 1];
#pragma unroll
                for (int o = 8; o; o >>= 1) {
                    e_s += __shfl_down(e_s, o, 16);
                    e_d += __shfl_down(e_d, o, 16);
                }
                if (lm == 0 && row < NN) {
                    int h = wn * 4 + hp;
                    es1[row * NH + h] = e_s;
                    ed1[row * NH + h] = e_d;
                }
            }
        }
    }
}

// ---------------- layer-1 softmax aggregate (+ ELU): 1 wave = 1 node, NO barriers/LDS ----------------
// lane = 32 feature-octets x 2 edge-parities. No max-subtraction (logits bounded, shift-invariant).
__global__ __launch_bounds__(256) void agg1(const u16* __restrict__ h1b, const float* __restrict__ es,
                                            const float* __restrict__ ed, const int* __restrict__ off,
                                            const int* __restrict__ csr_src, u16* __restrict__ out1b) {
    int wave = threadIdx.x >> 6;
    int lane = threadIdx.x & 63;
    int n = blockIdx.x * 4 + wave;      // NN % 4 == 0
    int fh = lane & 31;                 // features fh*8 .. fh*8+7
    int ep = lane >> 5;                 // edge parity
    int head = fh >> 2;
    int beg = off[n];
    int deg = off[n + 1] - beg;
    float edh = ed[n * NH + head];
    const u16* hbase = h1b + fh * 8;
    float acc[8] = {0.f, 0.f, 0.f, 0.f, 0.f, 0.f, 0.f, 0.f};
    float s_part = 0.f;
    for (int base = 0; base < deg; base += 16) {
        int nch = deg - base; if (nch > 16) nch = 16;
        int sv = (lane < nch) ? csr_src[beg + base + lane] : 0;
#pragma unroll
        for (int e = 0; e < 8; e++) {
            int ee = 2 * e + ep;
            int s = __shfl(sv, ee, 64);
            if (ee < nch) {
                float lg = es[s * NH + head] + edh;
                float p = __expf(lg > 0.f ? lg : NEG * lg);
                ushortx8 hv = *(const ushortx8*)(hbase + (size_t)s * HF);
                s_part += p;
#pragma unroll
                for (int i = 0; i < 8; i++) acc[i] += p * bf2f(hv[i]);
            }
        }
    }
    // combine parities: lanes 0..31 get totals
#pragma unroll
    for (int i = 0; i < 8; i++) acc[i] += __shfl_down(acc[i], 32, 64);
    s_part += __shfl_down(s_part, 32, 64);
    if (lane < 32) {
        float inv = s_part > 0.f ? 1.0f / s_part : 0.f;
        union { uintx4 u; ushortx8 v; } ob;
#pragma unroll
        for (int i = 0; i < 4; i++) {
            float v0 = acc[2 * i] * inv, v1 = acc[2 * i + 1] * inv;
            v0 = v0 > 0.f ? v0 : (__expf(v0) - 1.0f);   // fused ELU
            v1 = v1 > 0.f ? v1 : (__expf(v1) - 1.0f);
            ob.u[i] = (unsigned)f2bf(v0) | ((unsigned)f2bf(v1) << 16);
        }
        *(ushortx8*)(out1b + (size_t)n * HF + fh * 8) = ob.v;
    }
}

// ---------------- GEMM2 (1-wave MFMA) + layer-2 scores; h2 stored bf16 ----------------
__global__ __launch_bounds__(64) void gemm2_mfma(const u16* __restrict__ out1b, const u16* __restrict__ w2t,
                                                 const float* __restrict__ a2s, const float* __restrict__ a2d,
                                                 u16* __restrict__ h2b, float* __restrict__ es2,
                                                 float* __restrict__ ed2) {
    int lane = threadIdx.x;
    int lm = lane & 15, quad = lane >> 4;
    int nb = blockIdx.x * 16;
    floatx4 acc = (floatx4){0.f, 0.f, 0.f, 0.f};
    const u16* arow = out1b + (size_t)(nb + lm) * HF + quad * 8;
    const u16* brow = w2t + lm * HF + quad * 8;
#pragma unroll
    for (int kk = 0; kk < HF; kk += 32) {
        shortx8 af = *(const shortx8*)(arow + kk);
        shortx8 bf = *(const shortx8*)(brow + kk);
        acc = __builtin_amdgcn_mfma_f32_16x16x32_bf16(af, bf, acc, 0, 0, 0);
    }
    float a2sc = a2s[lm], a2dc = a2d[lm];
#pragma unroll
    for (int r = 0; r < 4; r++) {
        int n = nb + quad * 4 + r;
        float v = acc[r];
        h2b[n * NC + lm] = f2bf(v);
        float ps = v * a2sc, pd = v * a2dc;
#pragma unroll
        for (int o = 8; o; o >>= 1) {
            ps += __shfl_down(ps, o, 16);
            pd += __shfl_down(pd, o, 16);
        }
        if (lm == 0) { es2[n] = ps; ed2[n] = pd; }
    }
}

// ---------------- layer-2 aggregate + log_softmax: 16 nodes x 16 classes ----------------
__global__ __launch_bounds__(256) void agg2(const u16* __restrict__ h2b, const float* __restrict__ es2,
                                            const float* __restrict__ ed2, const int* __restrict__ off,
                                            const int* __restrict__ csr_src, float* __restrict__ out) {
    int t = threadIdx.x;
    int nid = blockIdx.x * 16 + (t >> 4);   // NN % 16 == 0
    int c = t & 15;
    int beg = off[nid];
    int deg = off[nid + 1] - beg;
    float edn = ed2[nid];
    float s = 0.f, acc = 0.f;
    for (int base = 0; base < deg; base += 16) {
        int nch = deg - base; if (nch > 16) nch = 16;
        int sv = 0;
        if (c < nch) sv = csr_src[beg + base + c];
        int sva[16];
#pragma unroll
        for (int e = 0; e < 16; e++) sva[e] = __shfl(sv, e, 16);
        float hva[16];
#pragma unroll
        for (int e = 0; e < 16; e++) hva[e] = bf2f(h2b[sva[e] * NC + c]);  // e>=nch: row 0, masked by p=0
        float p = 0.f;
        if (c < nch) p = __expf(lrelu(es2[sv] + edn));
        s += p;
        float pa[16];
#pragma unroll
        for (int e = 0; e < 16; e++) pa[e] = __shfl(p, e, 16);
#pragma unroll
        for (int e = 0; e < 16; e++) acc += pa[e] * hva[e];
    }
#pragma unroll
    for (int o = 8; o; o >>= 1) s += __shfl_down(s, o, 16);
    s = __shfl(s, 0, 16);
    float v = (s > 0.f) ? acc / s : 0.f;
    float m2 = v;
#pragma unroll
    for (int o = 8; o; o >>= 1) m2 = fmaxf(m2, __shfl_down(m2, o, 16));
    m2 = __shfl(m2, 0, 16);
    float se = __expf(v - m2);
#pragma unroll
    for (int o = 8; o; o >>= 1) se += __shfl_down(se, o, 16);
    se = __shfl(se, 0, 16);
    out[nid * NC + c] = v - m2 - __logf(se);
}

extern "C" void kernel_launch(void* const* d_in, const int* in_sizes, int n_in,
                              void* d_out, int out_size, void* d_ws, size_t ws_size,
                              hipStream_t stream) {
    const float* x   = (const float*)d_in[0];
    const float* W1  = (const float*)d_in[1];
    const float* a1s = (const float*)d_in[2];
    const float* a1d = (const float*)d_in[3];
    const float* W2  = (const float*)d_in[4];
    const float* a2s = (const float*)d_in[5];
    const float* a2d = (const float*)d_in[6];
    const int*   ei  = (const int*)d_in[7];
    const int* srcv = ei;
    const int* dstv = ei + EE;
    float* out = (float*)d_out;

    // workspace (~62 MB)
    u16* h1b    = (u16*)d_ws;                         // N*256 bf16
    u16* out1b  = h1b + (size_t)NN * HF;              // N*256 bf16
    float* es1  = (float*)(out1b + (size_t)NN * HF);  // N*8 interleaved
    float* ed1  = es1 + (size_t)NN * NH;              // N*8
    u16* h2b    = (u16*)(ed1 + (size_t)NN * NH);      // N*16 bf16
    float* es2v = (float*)(h2b + (size_t)NN * NC);    // N
    float* ed2v = es2v + NN;                          // N
    int* deg    = (int*)(ed2v + NN);                  // N   (deg+cursor contiguous: one memset)
    int* cursor = deg + NN;                           // N
    int* offs   = cursor + NN;                        // N+1
    int* csr    = offs + NN + 1;                      // E
    int* bsum   = csr + EE;                           // 256
    u16* w1t    = (u16*)(bsum + 256);                 // 256*512 bf16
    u16* w2t    = w1t + (size_t)HF * KIN;             // 16*256 bf16

    hipMemsetAsync(deg, 0, 2 * NN * sizeof(int), stream);
    count_deg_convw<<<(EE + 255) / 256, 256, 0, stream>>>(dstv, deg, W1, W2, w1t, w2t);
    scan_a<<<NB_SCAN, 256, 0, stream>>>(deg, bsum);
    scan_c<<<NB_SCAN, 256, 0, stream>>>(deg, bsum, offs);
    fill_csr<<<(EE + 255) / 256, 256, 0, stream>>>(srcv, dstv, offs, cursor, csr);
    gemm1_mfma<<<(NN + 127) / 128, 256, 0, stream>>>(x, w1t, h1b, a1s, a1d, es1, ed1);
    agg1<<<NN / 4, 256, 0, stream>>>(h1b, es1, ed1, offs, csr, out1b);
    gemm2_mfma<<<NN / 16, 64, 0, stream>>>(out1b, w2t, a2s, a2d, h2b, es2v, ed2v);
    agg2<<<NN / 16, 256, 0, stream>>>(h2b, es2v, ed2v, offs, csr, out);
}